// Round 15
// baseline (996.470 us; speedup 1.0000x reference)
//
#include <hip/hip_runtime.h>

#define NN 50000
#define HH 202
#define EE 100000
#define PMX 1024
#define NKT 7          // k-steps of 32 (K padded to 224; packs zero-padded)
#define PKS2 (16 * NKT * 64 * 8)   // ushorts per padded B pack (16 cf) = 57344
#define NEDG (6 * EE)
#define AFR (4 * NKT * 64 * 8)     // ushorts per fragment-order A tile = 14336

typedef __attribute__((ext_vector_type(8))) short short8;
typedef __attribute__((ext_vector_type(4))) float v4f;

__device__ __forceinline__ float sigf(float x) { return 1.0f / (1.0f + expf(-x)); }

__device__ __forceinline__ unsigned short f2bf(float x) {
    unsigned int u = __float_as_uint(x);
    unsigned int r = (u + 0x7fffu + ((u >> 16) & 1u)) >> 16;
    return (unsigned short)r;
}
__device__ __forceinline__ float bf2f(unsigned short u) {
    return __uint_as_float(((unsigned int)u) << 16);
}
__device__ __forceinline__ float bflo(unsigned int u) {      // element 2k   (low ushort)
    return __uint_as_float(u << 16);
}
__device__ __forceinline__ float bfhi(unsigned int u) {      // element 2k+1 (high ushort)
    return __uint_as_float(u & 0xffff0000u);
}
__device__ __forceinline__ unsigned int bfpack(float lo, float hi) {
    return (unsigned int)f2bf(lo) | ((unsigned int)f2bf(hi) << 16);
}

// gate[p][j] = bf16( 2*sigmoid(sum_k pt[p][k]*pos_W[k][j] + pos_b[j]) )
__global__ void gate_kernel(const float* __restrict__ pos_W, const float* __restrict__ pos_b,
                            unsigned short* __restrict__ gate) {
    int p = blockIdx.x;
    __shared__ float pt[HH];
    int t = threadIdx.x;
    if (t < HH) {
        float v;
        if (t < 101) {
            float invf = expf(-(2.0f * t / 202.0f) * 9.210340371976184f); // ln(10000)
            v = sinf((float)p * invf);
        } else {
            int k = t - 101;
            float invf = expf(-(2.0f * k / 202.0f) * 9.210340371976184f);
            v = cosf((float)p * invf);
        }
        pt[t] = v;
    }
    __syncthreads();
    for (int j = t; j < HH; j += blockDim.x) {
        float acc = pos_b[j];
        for (int k = 0; k < HH; ++k) acc += pt[k] * pos_W[k * HH + j];
        gate[p * HH + j] = f2bf(2.0f * sigf(acc));
    }
}

// Pack B into MFMA fragment order (16 cf, padded), f32 -> bf16; zeros for k,j >= 202.
// BP[((cf*NKT + kt)*64 + l)*8 + jj] = B[k][j], k = kt*32+(l>>4)*8+jj, j = cf*16+(l&15)
__global__ void pack_kernel(const float* __restrict__ S, int ldb, int row0, int col0, int mode,
                            unsigned short* __restrict__ BP) {
    int idx = blockIdx.x * blockDim.x + threadIdx.x;
    if (idx >= PKS2) return;
    int jj = idx & 7;
    int l = (idx >> 3) & 63;
    int r2 = idx >> 9;             // cf*NKT + kt, cf in 0..15
    int cf = r2 / NKT, kt = r2 - cf * NKT;
    int k = kt * 32 + ((l >> 4) << 3) + jj;
    int j = cf * 16 + (l & 15);
    float v = 0.0f;
    if (k < HH && j < HH)
        v = mode ? S[(size_t)(row0 + j) * HH + k] : S[(size_t)k * ldb + col0 + j];
    BP[idx] = f2bf(v);
}

__global__ void count_kernel(const int* __restrict__ el, int* __restrict__ cnt) {
    int idx = blockIdx.x * blockDim.x + threadIdx.x;
    if (idx >= NEDG) return;
    int ty = idx / EE, e = idx - ty * EE;
    int2 pr = (ty < 3) ? reinterpret_cast<const int2*>(el)[ty * EE + e]
                       : reinterpret_cast<const int2*>(el)[(ty - 3) * EE + e];
    int tg = (ty < 3) ? pr.y : pr.x;
    atomicAdd(&cnt[tg], 1);
}

__global__ void scan1_kernel(const int* __restrict__ cnt, int* __restrict__ off,
                             int* __restrict__ bsum) {
    __shared__ int sd[256];
    int t = threadIdx.x, i = blockIdx.x * 256 + t;
    int v = (i < NN) ? cnt[i] : 0;
    sd[t] = v;
    __syncthreads();
    for (int s = 1; s < 256; s <<= 1) {
        int u = (t >= s) ? sd[t - s] : 0;
        __syncthreads();
        sd[t] += u;
        __syncthreads();
    }
    if (i < NN) off[i] = sd[t] - v;
    if (t == 255) bsum[blockIdx.x] = sd[255];
}

__global__ void scan2_kernel(int* __restrict__ bsum, int nb) {
    __shared__ int sd[256];
    int t = threadIdx.x;
    int v = (t < nb) ? bsum[t] : 0;
    sd[t] = v;
    __syncthreads();
    for (int s = 1; s < 256; s <<= 1) {
        int u = (t >= s) ? sd[t - s] : 0;
        __syncthreads();
        sd[t] += u;
        __syncthreads();
    }
    if (t < nb) bsum[t] = sd[t] - v;   // exclusive
}

__global__ void scan3_kernel(int* __restrict__ off, const int* __restrict__ bsum,
                             int* __restrict__ cursor) {
    int i = blockIdx.x * 256 + threadIdx.x;
    if (i < NN) {
        int o = off[i] + bsum[blockIdx.x];
        off[i] = o;
        cursor[i] = o;
    }
    if (i == 0) off[NN] = NEDG;
}

__global__ void inv_kernel(const int* __restrict__ cnt, float* __restrict__ inv) {
    int n = blockIdx.x * blockDim.x + threadIdx.x;
    if (n < NN) inv[n] = 1.0f / (float)max(cnt[n], 1);
}

// EDG[slot] = src(17b) << 13 | ty(3b) << 10 | pos(10b), grouped by target via cursor
__global__ void fill_kernel(const int* __restrict__ el, const int* __restrict__ pl,
                            int* __restrict__ cursor, int* __restrict__ edg) {
    int idx = blockIdx.x * blockDim.x + threadIdx.x;
    if (idx >= NEDG) return;
    int ty = idx / EE, e = idx - ty * EE;
    int s, tg;
    if (ty < 3) {
        int2 pr = reinterpret_cast<const int2*>(el)[ty * EE + e];
        s = pr.x; tg = pr.y;
    } else {
        int2 pr = reinterpret_cast<const int2*>(el)[(ty - 3) * EE + e];
        s = pr.y; tg = pr.x;
    }
    int p = pl[(ty % 3) * EE + e];
    p = min(max(p, 0), PMX - 1);
    int slot = atomicAdd(&cursor[tg], 1);
    edg[slot] = (s << 13) | (ty << 10) | p;
}

// fragment-order LDS offset for element (row in [0,64), even k in [0,224)):
// slice rf=row>>4; within slice: [kt][lane=(k>>3&3)*16+(row&15)][j=k&7]
__device__ __forceinline__ int frag_off(int row, int k) {
    return (((row >> 4) * NKT + (k >> 5)) * 64 + ((k >> 3) & 3) * 16 + (row & 15)) * 8 + (k & 7);
}

// Shared multi-pack GEMM: O[p] = A @ B[p] (+ bias[p]), bf16 out.
// M=64/block, 512 threads = 8 waves: 2 row-groups (2 rf) x 4 col-groups (4 cf).
// A staged once in fragment-order LDS. c_lds shrunk to 32 rows (two rfi
// half-passes) -> LDS ~40.6KB -> 3 blocks/CU (24 waves) for latency hiding.
// Chunk copy-outs are whole-16-row linear uint4 streams (NN % 16 == 0).
__global__ __launch_bounds__(512, 6) void gemm9(
    const void* __restrict__ Asrc, int a_is_f32,
    const unsigned short* __restrict__ BPbase, int npack,
    const float* __restrict__ bias,
    unsigned short* __restrict__ O0, unsigned short* __restrict__ O1, int split) {
    __shared__ alignas(16) unsigned short a_lds[AFR];
    __shared__ alignas(16) unsigned short c_lds[32 * HH];
    const int t = threadIdx.x;
    const int w = t >> 6;
    const int l = t & 63;
    const int lm = l & 15, lh = l >> 4;
    const int rowg = w >> 2, colg = w & 3;
    const int cs = colg * 4;            // 0,4,8,12
    const int base = blockIdx.x * 64;

    if (a_is_f32) {
        const float* A = (const float*)Asrc;
        for (int idx = t; idx < 64 * 101; idx += 512) {
            int row = idx / 101;
            int c = idx - row * 101;
            int gn = base + row;
            float2 v = make_float2(0.f, 0.f);
            if (gn < NN) v = *reinterpret_cast<const float2*>(&A[(size_t)gn * HH + c * 2]);
            ushort2 bv; bv.x = f2bf(v.x); bv.y = f2bf(v.y);
            *reinterpret_cast<ushort2*>(&a_lds[frag_off(row, c * 2)]) = bv;
        }
    } else {
        const unsigned short* A = (const unsigned short*)Asrc;
        for (int idx = t; idx < 64 * 101; idx += 512) {
            int row = idx / 101;
            int c = idx - row * 101;
            int gn = base + row;
            ushort2 v; v.x = 0; v.y = 0;
            if (gn < NN) v = *reinterpret_cast<const ushort2*>(&A[(size_t)gn * HH + c * 2]);
            *reinterpret_cast<ushort2*>(&a_lds[frag_off(row, c * 2)]) = v;
        }
    }
    for (int idx = t; idx < 64 * 11; idx += 512) {
        int row = idx / 11;
        int c = idx - row * 11;
        ushort2 z; z.x = 0; z.y = 0;
        *reinterpret_cast<ushort2*>(&a_lds[frag_off(row, HH + c * 2)]) = z;
    }
    __syncthreads();

    const int aoff0 = (rowg * 2) * (NKT * 512) + l * 8;   // slice 2*rowg, kt=0, lane l
    const int aoff1 = aoff0 + NKT * 512;                  // slice 2*rowg+1

#pragma unroll 1
    for (int p = 0; p < npack; ++p) {
        const unsigned short* BP = BPbase + (size_t)p * PKS2 + (size_t)l * 8;
        const unsigned short* Bs0 = BP + (size_t)(cs + 0) * (NKT * 512);
        const unsigned short* Bs1 = BP + (size_t)(cs + 1) * (NKT * 512);
        const unsigned short* Bs2 = BP + (size_t)(cs + 2) * (NKT * 512);
        const unsigned short* Bs3 = BP + (size_t)(cs + 3) * (NKT * 512);

        v4f acc[4][2];
#pragma unroll
        for (int ci = 0; ci < 4; ++ci) {
            acc[ci][0] = (v4f){0.f, 0.f, 0.f, 0.f};
            acc[ci][1] = (v4f){0.f, 0.f, 0.f, 0.f};
        }

#pragma unroll
        for (int kt = 0; kt < NKT; ++kt) {
            const int ka = kt * 512;
            short8 b0 = *reinterpret_cast<const short8*>(Bs0 + ka);
            short8 b1 = *reinterpret_cast<const short8*>(Bs1 + ka);
            short8 b2 = *reinterpret_cast<const short8*>(Bs2 + ka);
            short8 b3 = *reinterpret_cast<const short8*>(Bs3 + ka);
            short8 a0 = *reinterpret_cast<const short8*>(&a_lds[aoff0 + ka]);
            short8 a1 = *reinterpret_cast<const short8*>(&a_lds[aoff1 + ka]);

            acc[0][0] = __builtin_amdgcn_mfma_f32_16x16x32_bf16(a0, b0, acc[0][0], 0, 0, 0);
            acc[0][1] = __builtin_amdgcn_mfma_f32_16x16x32_bf16(a1, b0, acc[0][1], 0, 0, 0);
            acc[1][0] = __builtin_amdgcn_mfma_f32_16x16x32_bf16(a0, b1, acc[1][0], 0, 0, 0);
            acc[1][1] = __builtin_amdgcn_mfma_f32_16x16x32_bf16(a1, b1, acc[1][1], 0, 0, 0);
            acc[2][0] = __builtin_amdgcn_mfma_f32_16x16x32_bf16(a0, b2, acc[2][0], 0, 0, 0);
            acc[2][1] = __builtin_amdgcn_mfma_f32_16x16x32_bf16(a1, b2, acc[2][1], 0, 0, 0);
            acc[3][0] = __builtin_amdgcn_mfma_f32_16x16x32_bf16(a0, b3, acc[3][0], 0, 0, 0);
            acc[3][1] = __builtin_amdgcn_mfma_f32_16x16x32_bf16(a1, b3, acc[3][1], 0, 0, 0);
        }

        unsigned short* slab = (p < split) ? O0 + (size_t)p * NN * HH
                                           : O1 + (size_t)(p - split) * NN * HH;
#pragma unroll 1
        for (int rfi = 0; rfi < 2; ++rfi) {
            __syncthreads();   // prior copy-out of c_lds complete
#pragma unroll
            for (int ci = 0; ci < 4; ++ci) {
                int col = (cs + ci) * 16 + lm;
                if (col < HH) {
                    float bb = bias ? bias[p * HH + col] : 0.0f;
#pragma unroll
                    for (int r = 0; r < 4; ++r)
                        c_lds[(rowg * 16 + lh * 4 + r) * HH + col] = f2bf(acc[ci][rfi][r] + bb);
                }
            }
            __syncthreads();
            int r0 = base + rfi * 16;           // c_lds rows 0..15  (rowg 0)
            int r1 = base + 32 + rfi * 16;      // c_lds rows 16..31 (rowg 1)
            const uint4* s = reinterpret_cast<const uint4*>(c_lds);
            if (r0 + 16 <= NN) {
                uint4* d0 = reinterpret_cast<uint4*>(slab + (size_t)r0 * HH);
                for (int i = t; i < 404; i += 512) d0[i] = s[i];
            }
            if (r1 + 16 <= NN) {
                uint4* d1 = reinterpret_cast<uint4*>(slab + (size_t)r1 * HH);
                for (int i = t; i < 404; i += 512) d1[i] = s[404 + i];
            }
        }
    }
}

// Fused GRU gate GEMM, dual-A: stages BOTH hsrc (f32->bf16) and msgb (bf16) tiles.
// Outputs 4 bias-baked slabs: p0 sr = msg@Wir + h@Whr + bir + bhr
//                             p1 sz = msg@Wiz + h@Whz + biz + bhz
//                             p2 hn = h@Whn + bhn
//                             p3 in = msg@Win + bin
__global__ __launch_bounds__(512, 4) void gemmG(
    const float* __restrict__ hsrc, const unsigned short* __restrict__ msgb,
    const unsigned short* __restrict__ BPih, const unsigned short* __restrict__ BPhh,
    const float* __restrict__ bih, const float* __restrict__ bhh,
    unsigned short* __restrict__ O) {
    __shared__ alignas(16) unsigned short a_lds[2 * AFR];   // h | msg
    __shared__ alignas(16) unsigned short c_lds[32 * HH];
    const int t = threadIdx.x;
    const int w = t >> 6;
    const int l = t & 63;
    const int lm = l & 15, lh = l >> 4;
    const int rowg = w >> 2, colg = w & 3;
    const int cs = colg * 4;
    const int base = blockIdx.x * 64;

    for (int idx = t; idx < 64 * 101; idx += 512) {
        int row = idx / 101;
        int c = idx - row * 101;
        int gn = base + row;
        float2 v = make_float2(0.f, 0.f);
        ushort2 m; m.x = 0; m.y = 0;
        if (gn < NN) {
            v = *reinterpret_cast<const float2*>(&hsrc[(size_t)gn * HH + c * 2]);
            m = *reinterpret_cast<const ushort2*>(&msgb[(size_t)gn * HH + c * 2]);
        }
        ushort2 bv; bv.x = f2bf(v.x); bv.y = f2bf(v.y);
        int fo = frag_off(row, c * 2);
        *reinterpret_cast<ushort2*>(&a_lds[fo]) = bv;
        *reinterpret_cast<ushort2*>(&a_lds[AFR + fo]) = m;
    }
    for (int idx = t; idx < 64 * 11; idx += 512) {
        int row = idx / 11;
        int c = idx - row * 11;
        ushort2 z; z.x = 0; z.y = 0;
        int fo = frag_off(row, HH + c * 2);
        *reinterpret_cast<ushort2*>(&a_lds[fo]) = z;
        *reinterpret_cast<ushort2*>(&a_lds[AFR + fo]) = z;
    }
    __syncthreads();

    const int aoffh = (rowg * 2) * (NKT * 512) + l * 8;
    const int aoffm = AFR + aoffh;

#pragma unroll 1
    for (int p = 0; p < 4; ++p) {
        const bool useH = (p != 3);
        const bool useM = (p != 2);
        const int bsel = (p < 2) ? p : 2;
        const unsigned short* Bh = BPhh + (size_t)bsel * PKS2 + (size_t)l * 8;
        const unsigned short* Bm = BPih + (size_t)bsel * PKS2 + (size_t)l * 8;

        v4f acc[4][2];
#pragma unroll
        for (int ci = 0; ci < 4; ++ci) {
            acc[ci][0] = (v4f){0.f, 0.f, 0.f, 0.f};
            acc[ci][1] = (v4f){0.f, 0.f, 0.f, 0.f};
        }

#pragma unroll 1
        for (int kt = 0; kt < NKT; ++kt) {
            const int ka = kt * 512;
            if (useH) {
                short8 a0 = *reinterpret_cast<const short8*>(&a_lds[aoffh + ka]);
                short8 a1 = *reinterpret_cast<const short8*>(&a_lds[aoffh + NKT * 512 + ka]);
#pragma unroll
                for (int ci = 0; ci < 4; ++ci) {
                    short8 b = *reinterpret_cast<const short8*>(
                        Bh + (size_t)(cs + ci) * (NKT * 512) + ka);
                    acc[ci][0] = __builtin_amdgcn_mfma_f32_16x16x32_bf16(a0, b, acc[ci][0], 0, 0, 0);
                    acc[ci][1] = __builtin_amdgcn_mfma_f32_16x16x32_bf16(a1, b, acc[ci][1], 0, 0, 0);
                }
            }
            if (useM) {
                short8 a0 = *reinterpret_cast<const short8*>(&a_lds[aoffm + ka]);
                short8 a1 = *reinterpret_cast<const short8*>(&a_lds[aoffm + NKT * 512 + ka]);
#pragma unroll
                for (int ci = 0; ci < 4; ++ci) {
                    short8 b = *reinterpret_cast<const short8*>(
                        Bm + (size_t)(cs + ci) * (NKT * 512) + ka);
                    acc[ci][0] = __builtin_amdgcn_mfma_f32_16x16x32_bf16(a0, b, acc[ci][0], 0, 0, 0);
                    acc[ci][1] = __builtin_amdgcn_mfma_f32_16x16x32_bf16(a1, b, acc[ci][1], 0, 0, 0);
                }
            }
        }

        unsigned short* slab = O + (size_t)p * NN * HH;
#pragma unroll 1
        for (int rfi = 0; rfi < 2; ++rfi) {
            __syncthreads();
#pragma unroll
            for (int ci = 0; ci < 4; ++ci) {
                int col = (cs + ci) * 16 + lm;
                if (col < HH) {
                    float bb = (p == 0) ? (bih[col] + bhh[col])
                             : (p == 1) ? (bih[202 + col] + bhh[202 + col])
                             : (p == 2) ? bhh[404 + col] : bih[404 + col];
#pragma unroll
                    for (int r = 0; r < 4; ++r)
                        c_lds[(rowg * 16 + lh * 4 + r) * HH + col] = f2bf(acc[ci][rfi][r] + bb);
                }
            }
            __syncthreads();
            int r0 = base + rfi * 16;
            int r1 = base + 32 + rfi * 16;
            const uint4* s = reinterpret_cast<const uint4*>(c_lds);
            if (r0 + 16 <= NN) {
                uint4* d0 = reinterpret_cast<uint4*>(slab + (size_t)r0 * HH);
                for (int i = t; i < 404; i += 512) d0[i] = s[i];
            }
            if (r1 + 16 <= NN) {
                uint4* d1 = reinterpret_cast<uint4*>(slab + (size_t)r1 * HH);
                for (int i = t; i < 404; i += 512) d1[i] = s[404 + i];
            }
        }
    }
}

// one wave per target node: MSG[n] (bf16) = inv[n] * sum_edges chunk[ty][src] * gate[pos]
// dword gathers: rows are 101 uints (404B, 4B-aligned); lane reads uints {lane, 64+lane}.
__global__ void agg_kernel(const unsigned short* __restrict__ CH0,
                           const unsigned short* __restrict__ CH45,
                           const int* __restrict__ off, const int* __restrict__ edg,
                           const unsigned short* __restrict__ gate,
                           const float* __restrict__ inv, unsigned short* __restrict__ msgb) {
    int n = blockIdx.x * 4 + (threadIdx.x >> 6);
    if (n >= NN) return;
    int lane = threadIdx.x & 63;
    int s0 = off[n], s1 = off[n + 1];
    const int u1 = 64 + lane;
    const bool u1ok = u1 < 101;
    float a0 = 0.f, a1 = 0.f, a2 = 0.f, a3 = 0.f;
    float b0 = 0.f, b1 = 0.f, b2 = 0.f, b3 = 0.f;
    int i = s0;
    for (; i + 1 < s1; i += 2) {
        int recA = edg[i], recB = edg[i + 1];
        int sA = recA >> 13, tyA = (recA >> 10) & 7, pA = recA & 1023;
        int sB = recB >> 13, tyB = (recB >> 10) & 7, pB = recB & 1023;
        const unsigned int* crA = reinterpret_cast<const unsigned int*>(
            ((tyA < 4) ? CH0 + (size_t)tyA * NN * HH : CH45 + (size_t)(tyA - 4) * NN * HH)
            + (size_t)sA * HH);
        const unsigned int* crB = reinterpret_cast<const unsigned int*>(
            ((tyB < 4) ? CH0 + (size_t)tyB * NN * HH : CH45 + (size_t)(tyB - 4) * NN * HH)
            + (size_t)sB * HH);
        const unsigned int* grA = reinterpret_cast<const unsigned int*>(gate + (size_t)pA * HH);
        const unsigned int* grB = reinterpret_cast<const unsigned int*>(gate + (size_t)pB * HH);
        unsigned int cA0 = crA[lane], gA0 = grA[lane];
        unsigned int cB0 = crB[lane], gB0 = grB[lane];
        a0 += bflo(cA0) * bflo(gA0);
        a1 += bfhi(cA0) * bfhi(gA0);
        b0 += bflo(cB0) * bflo(gB0);
        b1 += bfhi(cB0) * bfhi(gB0);
        if (u1ok) {
            unsigned int cA1 = crA[u1], gA1 = grA[u1];
            unsigned int cB1 = crB[u1], gB1 = grB[u1];
            a2 += bflo(cA1) * bflo(gA1);
            a3 += bfhi(cA1) * bfhi(gA1);
            b2 += bflo(cB1) * bflo(gB1);
            b3 += bfhi(cB1) * bfhi(gB1);
        }
    }
    if (i < s1) {
        int rec = edg[i];
        int src = rec >> 13, ty = (rec >> 10) & 7, p = rec & 1023;
        const unsigned int* cr = reinterpret_cast<const unsigned int*>(
            ((ty < 4) ? CH0 + (size_t)ty * NN * HH : CH45 + (size_t)(ty - 4) * NN * HH)
            + (size_t)src * HH);
        const unsigned int* gr = reinterpret_cast<const unsigned int*>(gate + (size_t)p * HH);
        unsigned int c0 = cr[lane], g0 = gr[lane];
        a0 += bflo(c0) * bflo(g0);
        a1 += bfhi(c0) * bfhi(g0);
        if (u1ok) {
            unsigned int c1 = cr[u1], g1 = gr[u1];
            a2 += bflo(c1) * bflo(g1);
            a3 += bfhi(c1) * bfhi(g1);
        }
    }
    float iv = inv[n];
    unsigned int* mr = reinterpret_cast<unsigned int*>(msgb + (size_t)n * HH);
    mr[lane] = bfpack((a0 + b0) * iv, (a1 + b1) * iv);
    if (u1ok) mr[u1] = bfpack((a2 + b2) * iv, (a3 + b3) * iv);
}

// Streaming GRU elementwise over 4 bias-baked slabs {sr, sz, hn, in}:
// r=sig(sr); z=sig(sz); n=tanh(in + r*hn); h' = (1-z)*n + z*hsrc.
__global__ void gru_ew(float* __restrict__ h, const float* __restrict__ hsrc,
                       const unsigned short* __restrict__ G) {
    int n = blockIdx.x * 4 + (threadIdx.x >> 6);
    if (n >= NN) return;
    int lane = threadIdx.x & 63;
    const size_t NHu = (size_t)NN * HH / 2;      // slab stride in uints
    const unsigned int* Gu = reinterpret_cast<const unsigned int*>(G) + (size_t)n * 101;
    const float2* hsp = reinterpret_cast<const float2*>(hsrc + (size_t)n * HH);
    float2* hp = reinterpret_cast<float2*>(h + (size_t)n * HH);
#pragma unroll
    for (int q = 0; q < 2; ++q) {
        int u = lane + q * 64;
        if (u < 101) {
            unsigned int sr = Gu[u];
            unsigned int sz = Gu[NHu + u];
            unsigned int hn = Gu[2 * NHu + u];
            unsigned int in_ = Gu[3 * NHu + u];
            float2 hv = hsp[u];
            float r0 = sigf(bflo(sr));
            float r1 = sigf(bfhi(sr));
            float z0 = sigf(bflo(sz));
            float z1 = sigf(bfhi(sz));
            float n0 = tanhf(bflo(in_) + r0 * bflo(hn));
            float n1 = tanhf(bfhi(in_) + r1 * bfhi(hn));
            float2 hvo;
            hvo.x = (1.0f - z0) * n0 + z0 * hv.x;
            hvo.y = (1.0f - z1) * n1 + z1 * hv.y;
            hp[u] = hvo;
        }
    }
}

extern "C" void kernel_launch(void* const* d_in, const int* in_sizes, int n_in,
                              void* d_out, int out_size, void* d_ws, size_t ws_size,
                              hipStream_t stream) {
    const float* node_states = (const float*)d_in[0];
    const int*   el          = (const int*)d_in[1];
    const int*   pl          = (const int*)d_in[2];
    const float* msg_W       = (const float*)d_in[3];
    const float* msg_b       = (const float*)d_in[4];
    const float* pos_W       = (const float*)d_in[5];
    const float* pos_b       = (const float*)d_in[6];
    const float* gWih        = (const float*)d_in[7];
    const float* gWhh        = (const float*)d_in[8];
    const float* gbih        = (const float*)d_in[9];
    const float* gbhh        = (const float*)d_in[10];

    float* out  = (float*)d_out;
    float* h    = out;                               // [N,H] final h
    float* out2 = out + (size_t)NN * HH;             // 2 bf16 slabs during steps; node_states at end

    unsigned short* CH0  = (unsigned short*)d_ws;                    // 4 slabs bf16 [N,H]
    unsigned short* CH45 = (unsigned short*)out2;                    // 2 slabs bf16 [N,H]
    unsigned short* MSGB = CH0 + (size_t)4 * NN * HH;                // [N,H] bf16
    unsigned short* GATE = MSGB + (size_t)NN * HH;                   // [1024,H] bf16
    float* INV  = (float*)(GATE + (size_t)PMX * HH + 8);             // [N]
    int* CNT    = (int*)(INV + NN);                                  // [N]
    int* OFF    = CNT + NN;                                          // [N+4]
    int* CUR    = OFF + NN + 4;                                      // [N]
    int* BS     = CUR + NN;                                          // [256]
    int* EDG    = BS + 256;                                          // [600000]
    unsigned short* BPA = (unsigned short*)(EDG + NEDG);             // 12 padded packs
    unsigned short* BPp  = BPA;                                      // 6 prop packs
    unsigned short* BPih = BPA + (size_t)6 * PKS2;                   // ir,iz,in (contig)
    unsigned short* BPhh = BPA + (size_t)9 * PKS2;                   // hr,hz,hn (contig)

    const size_t NH = (size_t)NN * HH;
    hipMemsetAsync(CNT, 0, NN * sizeof(int), stream);
    gate_kernel<<<PMX, 256, 0, stream>>>(pos_W, pos_b, GATE);
    const int pkb = (PKS2 + 255) / 256;
    for (int ty = 0; ty < 6; ++ty)
        pack_kernel<<<pkb, 256, 0, stream>>>(msg_W, 1212, 0, ty * HH, 0, BPp + (size_t)ty * PKS2);
    pack_kernel<<<pkb, 256, 0, stream>>>(gWih, 0, 0,   0, 1, BPih);
    pack_kernel<<<pkb, 256, 0, stream>>>(gWih, 0, 202, 0, 1, BPih + PKS2);
    pack_kernel<<<pkb, 256, 0, stream>>>(gWih, 0, 404, 0, 1, BPih + 2 * PKS2);
    pack_kernel<<<pkb, 256, 0, stream>>>(gWhh, 0, 0,   0, 1, BPhh);
    pack_kernel<<<pkb, 256, 0, stream>>>(gWhh, 0, 202, 0, 1, BPhh + PKS2);
    pack_kernel<<<pkb, 256, 0, stream>>>(gWhh, 0, 404, 0, 1, BPhh + 2 * PKS2);

    const int nsb = (NN + 255) / 256;    // 196
    count_kernel<<<(NEDG + 255) / 256, 256, 0, stream>>>(el, CNT);
    scan1_kernel<<<nsb, 256, 0, stream>>>(CNT, OFF, BS);
    scan2_kernel<<<1, 256, 0, stream>>>(BS, nsb);
    scan3_kernel<<<nsb, 256, 0, stream>>>(OFF, BS, CUR);
    inv_kernel<<<nsb, 256, 0, stream>>>(CNT, INV);
    fill_kernel<<<(NEDG + 255) / 256, 256, 0, stream>>>(el, pl, CUR, EDG);

    const int gblocks = (NN + 63) / 64;  // 782
    const int ewblocks = (NN + 3) / 4;
    for (int step = 0; step < 2; ++step) {
        const float* hsrc = (step == 0) ? node_states : h;
        // 6 chunk GEMMs from h
        gemm9<<<gblocks, 512, 0, stream>>>(hsrc, 1, BPp, 6, msg_b, CH0, CH45, 4);
        // edge aggregation -> MSGB (bf16)
        agg_kernel<<<ewblocks, 256, 0, stream>>>(CH0, CH45, OFF, EDG, GATE, INV, MSGB);
        // fused gate GEMM (dual-A): sr, sz, hn, in -> CH0 slabs 0..3 (bias-baked)
        gemmG<<<gblocks, 512, 0, stream>>>(hsrc, MSGB, BPih, BPhh, gbih, gbhh, CH0);
        // streaming GRU elementwise, in-place h
        gru_ew<<<ewblocks, 256, 0, stream>>>(h, hsrc, CH0);
    }
    hipMemcpyAsync(out2, node_states, NH * sizeof(float), hipMemcpyDeviceToDevice, stream);
}

// Round 16
// 632.738 us; speedup vs baseline: 1.5749x; 1.5749x over previous
//
#include <hip/hip_runtime.h>

#define NN 50000
#define HH 202
#define EE 100000
#define PMX 1024
#define NKT 7          // k-steps of 32 (K padded to 224; packs zero-padded)
#define PKS2 (16 * NKT * 64 * 8)   // ushorts per padded B pack (16 cf) = 57344
#define NEDG (6 * EE)
#define AFR (4 * NKT * 64 * 8)     // ushorts per fragment-order A tile = 14336

typedef __attribute__((ext_vector_type(8))) short short8;
typedef __attribute__((ext_vector_type(4))) float v4f;

__device__ __forceinline__ float sigf(float x) { return 1.0f / (1.0f + expf(-x)); }

__device__ __forceinline__ unsigned short f2bf(float x) {
    unsigned int u = __float_as_uint(x);
    unsigned int r = (u + 0x7fffu + ((u >> 16) & 1u)) >> 16;
    return (unsigned short)r;
}
__device__ __forceinline__ float bf2f(unsigned short u) {
    return __uint_as_float(((unsigned int)u) << 16);
}
__device__ __forceinline__ float bflo(unsigned int u) {      // element 2k   (low ushort)
    return __uint_as_float(u << 16);
}
__device__ __forceinline__ float bfhi(unsigned int u) {      // element 2k+1 (high ushort)
    return __uint_as_float(u & 0xffff0000u);
}
__device__ __forceinline__ unsigned int bfpack(float lo, float hi) {
    return (unsigned int)f2bf(lo) | ((unsigned int)f2bf(hi) << 16);
}

// gate[p][j] = bf16( 2*sigmoid(sum_k pt[p][k]*pos_W[k][j] + pos_b[j]) )
__global__ void gate_kernel(const float* __restrict__ pos_W, const float* __restrict__ pos_b,
                            unsigned short* __restrict__ gate) {
    int p = blockIdx.x;
    __shared__ float pt[HH];
    int t = threadIdx.x;
    if (t < HH) {
        float v;
        if (t < 101) {
            float invf = expf(-(2.0f * t / 202.0f) * 9.210340371976184f); // ln(10000)
            v = sinf((float)p * invf);
        } else {
            int k = t - 101;
            float invf = expf(-(2.0f * k / 202.0f) * 9.210340371976184f);
            v = cosf((float)p * invf);
        }
        pt[t] = v;
    }
    __syncthreads();
    for (int j = t; j < HH; j += blockDim.x) {
        float acc = pos_b[j];
        for (int k = 0; k < HH; ++k) acc += pt[k] * pos_W[k * HH + j];
        gate[p * HH + j] = f2bf(2.0f * sigf(acc));
    }
}

// Pack B into MFMA fragment order (16 cf, padded), f32 -> bf16; zeros for k,j >= 202.
// BP[((cf*NKT + kt)*64 + l)*8 + jj] = B[k][j], k = kt*32+(l>>4)*8+jj, j = cf*16+(l&15)
__global__ void pack_kernel(const float* __restrict__ S, int ldb, int row0, int col0, int mode,
                            unsigned short* __restrict__ BP) {
    int idx = blockIdx.x * blockDim.x + threadIdx.x;
    if (idx >= PKS2) return;
    int jj = idx & 7;
    int l = (idx >> 3) & 63;
    int r2 = idx >> 9;             // cf*NKT + kt, cf in 0..15
    int cf = r2 / NKT, kt = r2 - cf * NKT;
    int k = kt * 32 + ((l >> 4) << 3) + jj;
    int j = cf * 16 + (l & 15);
    float v = 0.0f;
    if (k < HH && j < HH)
        v = mode ? S[(size_t)(row0 + j) * HH + k] : S[(size_t)k * ldb + col0 + j];
    BP[idx] = f2bf(v);
}

__global__ void count_kernel(const int* __restrict__ el, int* __restrict__ cnt) {
    int idx = blockIdx.x * blockDim.x + threadIdx.x;
    if (idx >= NEDG) return;
    int ty = idx / EE, e = idx - ty * EE;
    int2 pr = (ty < 3) ? reinterpret_cast<const int2*>(el)[ty * EE + e]
                       : reinterpret_cast<const int2*>(el)[(ty - 3) * EE + e];
    int tg = (ty < 3) ? pr.y : pr.x;
    atomicAdd(&cnt[tg], 1);
}

__global__ void scan1_kernel(const int* __restrict__ cnt, int* __restrict__ off,
                             int* __restrict__ bsum) {
    __shared__ int sd[256];
    int t = threadIdx.x, i = blockIdx.x * 256 + t;
    int v = (i < NN) ? cnt[i] : 0;
    sd[t] = v;
    __syncthreads();
    for (int s = 1; s < 256; s <<= 1) {
        int u = (t >= s) ? sd[t - s] : 0;
        __syncthreads();
        sd[t] += u;
        __syncthreads();
    }
    if (i < NN) off[i] = sd[t] - v;
    if (t == 255) bsum[blockIdx.x] = sd[255];
}

__global__ void scan2_kernel(int* __restrict__ bsum, int nb) {
    __shared__ int sd[256];
    int t = threadIdx.x;
    int v = (t < nb) ? bsum[t] : 0;
    sd[t] = v;
    __syncthreads();
    for (int s = 1; s < 256; s <<= 1) {
        int u = (t >= s) ? sd[t - s] : 0;
        __syncthreads();
        sd[t] += u;
        __syncthreads();
    }
    if (t < nb) bsum[t] = sd[t] - v;   // exclusive
}

__global__ void scan3_kernel(int* __restrict__ off, const int* __restrict__ bsum,
                             int* __restrict__ cursor) {
    int i = blockIdx.x * 256 + threadIdx.x;
    if (i < NN) {
        int o = off[i] + bsum[blockIdx.x];
        off[i] = o;
        cursor[i] = o;
    }
    if (i == 0) off[NN] = NEDG;
}

__global__ void inv_kernel(const int* __restrict__ cnt, float* __restrict__ inv) {
    int n = blockIdx.x * blockDim.x + threadIdx.x;
    if (n < NN) inv[n] = 1.0f / (float)max(cnt[n], 1);
}

// EDG[slot] = src(17b) << 13 | ty(3b) << 10 | pos(10b), grouped by target via cursor
__global__ void fill_kernel(const int* __restrict__ el, const int* __restrict__ pl,
                            int* __restrict__ cursor, int* __restrict__ edg) {
    int idx = blockIdx.x * blockDim.x + threadIdx.x;
    if (idx >= NEDG) return;
    int ty = idx / EE, e = idx - ty * EE;
    int s, tg;
    if (ty < 3) {
        int2 pr = reinterpret_cast<const int2*>(el)[ty * EE + e];
        s = pr.x; tg = pr.y;
    } else {
        int2 pr = reinterpret_cast<const int2*>(el)[(ty - 3) * EE + e];
        s = pr.y; tg = pr.x;
    }
    int p = pl[(ty % 3) * EE + e];
    p = min(max(p, 0), PMX - 1);
    int slot = atomicAdd(&cursor[tg], 1);
    edg[slot] = (s << 13) | (ty << 10) | p;
}

// fragment-order LDS offset for element (row in [0,64), even k in [0,224)):
// slice rf=row>>4; within slice: [kt][lane=(k>>3&3)*16+(row&15)][j=k&7]
__device__ __forceinline__ int frag_off(int row, int k) {
    return (((row >> 4) * NKT + (k >> 5)) * 64 + ((k >> 3) & 3) * 16 + (row & 15)) * 8 + (k & 7);
}

// Shared multi-pack GEMM: O[p] = A @ B[p] (+ bias[p]), bf16 out.
// M=64/block, 512 threads = 8 waves: 2 row-groups (2 rf) x 4 col-groups (4 cf,
// packs padded to 16 cf -> branch-free). A staged once in fragment-order LDS
// (lane-contiguous conflict-free ds_read_b128). B streamed from L2 with depth-2
// prefetch. Output staged in c_lds -> linear uint4 coalesced copy-out.
__global__ __launch_bounds__(512, 4) void gemm9(
    const void* __restrict__ Asrc, int a_is_f32,
    const unsigned short* __restrict__ BPbase, int npack,
    const float* __restrict__ bias,
    unsigned short* __restrict__ O0, unsigned short* __restrict__ O1, int split) {
    __shared__ alignas(16) unsigned short a_lds[AFR];
    __shared__ alignas(16) unsigned short c_lds[64 * HH];
    const int t = threadIdx.x;
    const int w = t >> 6;
    const int l = t & 63;
    const int lm = l & 15, lh = l >> 4;
    const int rowg = w >> 2, colg = w & 3;
    const int cs = colg * 4;            // 0,4,8,12
    const int base = blockIdx.x * 64;
    const int vrows = min(64, NN - base);
    const int nu4 = (vrows * 101) >> 2;     // uint4 per bf16 out tile

    if (a_is_f32) {
        const float* A = (const float*)Asrc;
        for (int idx = t; idx < 64 * 101; idx += 512) {
            int row = idx / 101;
            int c = idx - row * 101;
            int gn = base + row;
            float2 v = make_float2(0.f, 0.f);
            if (gn < NN) v = *reinterpret_cast<const float2*>(&A[(size_t)gn * HH + c * 2]);
            ushort2 bv; bv.x = f2bf(v.x); bv.y = f2bf(v.y);
            *reinterpret_cast<ushort2*>(&a_lds[frag_off(row, c * 2)]) = bv;
        }
    } else {
        const unsigned short* A = (const unsigned short*)Asrc;
        for (int idx = t; idx < 64 * 101; idx += 512) {
            int row = idx / 101;
            int c = idx - row * 101;
            int gn = base + row;
            ushort2 v; v.x = 0; v.y = 0;
            if (gn < NN) v = *reinterpret_cast<const ushort2*>(&A[(size_t)gn * HH + c * 2]);
            *reinterpret_cast<ushort2*>(&a_lds[frag_off(row, c * 2)]) = v;
        }
    }
    for (int idx = t; idx < 64 * 11; idx += 512) {
        int row = idx / 11;
        int c = idx - row * 11;
        ushort2 z; z.x = 0; z.y = 0;
        *reinterpret_cast<ushort2*>(&a_lds[frag_off(row, HH + c * 2)]) = z;
    }
    __syncthreads();

    const int aoff0 = (rowg * 2) * (NKT * 512) + l * 8;   // slice 2*rowg, kt=0, lane l
    const int aoff1 = aoff0 + NKT * 512;                  // slice 2*rowg+1

#pragma unroll 1
    for (int p = 0; p < npack; ++p) {
        const unsigned short* BP = BPbase + (size_t)p * PKS2 + (size_t)l * 8;
        const unsigned short* Bs0 = BP + (size_t)(cs + 0) * (NKT * 512);
        const unsigned short* Bs1 = BP + (size_t)(cs + 1) * (NKT * 512);
        const unsigned short* Bs2 = BP + (size_t)(cs + 2) * (NKT * 512);
        const unsigned short* Bs3 = BP + (size_t)(cs + 3) * (NKT * 512);

        v4f acc[4][2];
#pragma unroll
        for (int ci = 0; ci < 4; ++ci) {
            acc[ci][0] = (v4f){0.f, 0.f, 0.f, 0.f};
            acc[ci][1] = (v4f){0.f, 0.f, 0.f, 0.f};
        }

        // B prefetch depth-2: bA = kt, bB = kt+1
        short8 bA0 = *reinterpret_cast<const short8*>(Bs0);
        short8 bA1 = *reinterpret_cast<const short8*>(Bs1);
        short8 bA2 = *reinterpret_cast<const short8*>(Bs2);
        short8 bA3 = *reinterpret_cast<const short8*>(Bs3);
        short8 bB0 = *reinterpret_cast<const short8*>(Bs0 + 512);
        short8 bB1 = *reinterpret_cast<const short8*>(Bs1 + 512);
        short8 bB2 = *reinterpret_cast<const short8*>(Bs2 + 512);
        short8 bB3 = *reinterpret_cast<const short8*>(Bs3 + 512);
        short8 ac0 = *reinterpret_cast<const short8*>(&a_lds[aoff0]);
        short8 ac1 = *reinterpret_cast<const short8*>(&a_lds[aoff1]);

#pragma unroll
        for (int kt = 0; kt < NKT; ++kt) {
            const int k2 = (kt + 2 <= 6) ? (kt + 2) : 6;
            const int ka2 = k2 * 512;
            short8 bC0 = *reinterpret_cast<const short8*>(Bs0 + ka2);
            short8 bC1 = *reinterpret_cast<const short8*>(Bs1 + ka2);
            short8 bC2 = *reinterpret_cast<const short8*>(Bs2 + ka2);
            short8 bC3 = *reinterpret_cast<const short8*>(Bs3 + ka2);
            const int kn = (kt + 1 <= 6) ? (kt + 1) : 6;
            short8 an0 = *reinterpret_cast<const short8*>(&a_lds[aoff0 + kn * 512]);
            short8 an1 = *reinterpret_cast<const short8*>(&a_lds[aoff1 + kn * 512]);

            acc[0][0] = __builtin_amdgcn_mfma_f32_16x16x32_bf16(ac0, bA0, acc[0][0], 0, 0, 0);
            acc[0][1] = __builtin_amdgcn_mfma_f32_16x16x32_bf16(ac1, bA0, acc[0][1], 0, 0, 0);
            acc[1][0] = __builtin_amdgcn_mfma_f32_16x16x32_bf16(ac0, bA1, acc[1][0], 0, 0, 0);
            acc[1][1] = __builtin_amdgcn_mfma_f32_16x16x32_bf16(ac1, bA1, acc[1][1], 0, 0, 0);
            acc[2][0] = __builtin_amdgcn_mfma_f32_16x16x32_bf16(ac0, bA2, acc[2][0], 0, 0, 0);
            acc[2][1] = __builtin_amdgcn_mfma_f32_16x16x32_bf16(ac1, bA2, acc[2][1], 0, 0, 0);
            acc[3][0] = __builtin_amdgcn_mfma_f32_16x16x32_bf16(ac0, bA3, acc[3][0], 0, 0, 0);
            acc[3][1] = __builtin_amdgcn_mfma_f32_16x16x32_bf16(ac1, bA3, acc[3][1], 0, 0, 0);

            ac0 = an0; ac1 = an1;
            bA0 = bB0; bA1 = bB1; bA2 = bB2; bA3 = bB3;
            bB0 = bC0; bB1 = bC1; bB2 = bC2; bB3 = bC3;
        }

        __syncthreads();   // prior pack's copy-out complete before c_lds overwrite
#pragma unroll
        for (int ci = 0; ci < 4; ++ci) {
            int col = (cs + ci) * 16 + lm;
            if (col < HH) {
                float bb = bias ? bias[p * HH + col] : 0.0f;
#pragma unroll
                for (int rfi = 0; rfi < 2; ++rfi) {
#pragma unroll
                    for (int r = 0; r < 4; ++r)
                        c_lds[(rowg * 32 + rfi * 16 + lh * 4 + r) * HH + col] =
                            f2bf(acc[ci][rfi][r] + bb);
                }
            }
        }
        __syncthreads();

        unsigned short* slab = (p < split) ? O0 + (size_t)p * NN * HH
                                           : O1 + (size_t)(p - split) * NN * HH;
        uint4* dst = reinterpret_cast<uint4*>(slab + (size_t)base * HH);
        const uint4* srcp = reinterpret_cast<const uint4*>(c_lds);
        for (int i = t; i < nu4; i += 512) dst[i] = srcp[i];
    }
}

// one wave per target node: MSG[n] (bf16) = inv[n] * sum_edges chunk[ty][src] * gate[pos]
// dword gathers: rows are 101 uints (404B, 4B-aligned); lane reads uints {lane, 64+lane}.
__global__ void agg_kernel(const unsigned short* __restrict__ CH0,
                           const unsigned short* __restrict__ CH45,
                           const int* __restrict__ off, const int* __restrict__ edg,
                           const unsigned short* __restrict__ gate,
                           const float* __restrict__ inv, unsigned short* __restrict__ msgb) {
    int n = blockIdx.x * 4 + (threadIdx.x >> 6);
    if (n >= NN) return;
    int lane = threadIdx.x & 63;
    int s0 = off[n], s1 = off[n + 1];
    const int u1 = 64 + lane;
    const bool u1ok = u1 < 101;
    float a0 = 0.f, a1 = 0.f, a2 = 0.f, a3 = 0.f;   // edge-set A: u0.lo, u0.hi, u1.lo, u1.hi
    float b0 = 0.f, b1 = 0.f, b2 = 0.f, b3 = 0.f;   // edge-set B
    int i = s0;
    for (; i + 1 < s1; i += 2) {
        int recA = edg[i], recB = edg[i + 1];
        int sA = recA >> 13, tyA = (recA >> 10) & 7, pA = recA & 1023;
        int sB = recB >> 13, tyB = (recB >> 10) & 7, pB = recB & 1023;
        const unsigned int* crA = reinterpret_cast<const unsigned int*>(
            ((tyA < 4) ? CH0 + (size_t)tyA * NN * HH : CH45 + (size_t)(tyA - 4) * NN * HH)
            + (size_t)sA * HH);
        const unsigned int* crB = reinterpret_cast<const unsigned int*>(
            ((tyB < 4) ? CH0 + (size_t)tyB * NN * HH : CH45 + (size_t)(tyB - 4) * NN * HH)
            + (size_t)sB * HH);
        const unsigned int* grA = reinterpret_cast<const unsigned int*>(gate + (size_t)pA * HH);
        const unsigned int* grB = reinterpret_cast<const unsigned int*>(gate + (size_t)pB * HH);
        unsigned int cA0 = crA[lane], gA0 = grA[lane];
        unsigned int cB0 = crB[lane], gB0 = grB[lane];
        a0 += bflo(cA0) * bflo(gA0);
        a1 += bfhi(cA0) * bfhi(gA0);
        b0 += bflo(cB0) * bflo(gB0);
        b1 += bfhi(cB0) * bfhi(gB0);
        if (u1ok) {
            unsigned int cA1 = crA[u1], gA1 = grA[u1];
            unsigned int cB1 = crB[u1], gB1 = grB[u1];
            a2 += bflo(cA1) * bflo(gA1);
            a3 += bfhi(cA1) * bfhi(gA1);
            b2 += bflo(cB1) * bflo(gB1);
            b3 += bfhi(cB1) * bfhi(gB1);
        }
    }
    if (i < s1) {
        int rec = edg[i];
        int src = rec >> 13, ty = (rec >> 10) & 7, p = rec & 1023;
        const unsigned int* cr = reinterpret_cast<const unsigned int*>(
            ((ty < 4) ? CH0 + (size_t)ty * NN * HH : CH45 + (size_t)(ty - 4) * NN * HH)
            + (size_t)src * HH);
        const unsigned int* gr = reinterpret_cast<const unsigned int*>(gate + (size_t)p * HH);
        unsigned int c0 = cr[lane], g0 = gr[lane];
        a0 += bflo(c0) * bflo(g0);
        a1 += bfhi(c0) * bfhi(g0);
        if (u1ok) {
            unsigned int c1 = cr[u1], g1 = gr[u1];
            a2 += bflo(c1) * bflo(g1);
            a3 += bfhi(c1) * bfhi(g1);
        }
    }
    float iv = inv[n];
    unsigned int* mr = reinterpret_cast<unsigned int*>(msgb + (size_t)n * HH);
    mr[lane] = bfpack((a0 + b0) * iv, (a1 + b1) * iv);
    if (u1ok) mr[u1] = bfpack((a2 + b2) * iv, (a3 + b3) * iv);
}

// Streaming GRU elementwise, vectorized: lane handles elements {2u, 2u+1} for
// u in {lane, 64+lane}. All slab reads are uint (2 bf16); h/hsrc as float2.
__global__ void gru_ew(float* __restrict__ h, const float* __restrict__ hsrc,
                       const unsigned short* __restrict__ GH,   // 3 slabs: hr,hz,hn
                       const unsigned short* __restrict__ GIr,  // 1 slab
                       const unsigned short* __restrict__ GIzn, // 2 slabs: iz,in
                       const float* __restrict__ bih, const float* __restrict__ bhh) {
    int n = blockIdx.x * 4 + (threadIdx.x >> 6);
    if (n >= NN) return;
    int lane = threadIdx.x & 63;
    const size_t NHu = (size_t)NN * HH / 2;      // slab stride in uints
    const unsigned int* GHu  = reinterpret_cast<const unsigned int*>(GH)  + (size_t)n * 101;
    const unsigned int* GIru = reinterpret_cast<const unsigned int*>(GIr) + (size_t)n * 101;
    const unsigned int* GIzu = reinterpret_cast<const unsigned int*>(GIzn) + (size_t)n * 101;
    const float2* hsp = reinterpret_cast<const float2*>(hsrc + (size_t)n * HH);
    float2* hp = reinterpret_cast<float2*>(h + (size_t)n * HH);
    const float2* bihp = reinterpret_cast<const float2*>(bih);
    const float2* bhhp = reinterpret_cast<const float2*>(bhh);
#pragma unroll
    for (int q = 0; q < 2; ++q) {
        int u = lane + q * 64;
        if (u < 101) {
            unsigned int ghr = GHu[u];
            unsigned int ghz = GHu[NHu + u];
            unsigned int ghn = GHu[2 * NHu + u];
            unsigned int gir = GIru[u];
            unsigned int giz = GIzu[u];
            unsigned int gin = GIzu[NHu + u];
            float2 br = bihp[u], bhr = bhhp[u];
            float2 bz = bihp[101 + u], bhz = bhhp[101 + u];
            float2 bn = bihp[202 + u], bhn = bhhp[202 + u];
            float2 hv = hsp[u];
            float r0 = sigf(bflo(gir) + bflo(ghr) + br.x + bhr.x);
            float r1 = sigf(bfhi(gir) + bfhi(ghr) + br.y + bhr.y);
            float z0 = sigf(bflo(giz) + bflo(ghz) + bz.x + bhz.x);
            float z1 = sigf(bfhi(giz) + bfhi(ghz) + bz.y + bhz.y);
            float n0 = tanhf(bflo(gin) + bn.x + r0 * (bflo(ghn) + bhn.x));
            float n1 = tanhf(bfhi(gin) + bn.y + r1 * (bfhi(ghn) + bhn.y));
            float2 hvo;
            hvo.x = (1.0f - z0) * n0 + z0 * hv.x;
            hvo.y = (1.0f - z1) * n1 + z1 * hv.y;
            hp[u] = hvo;
        }
    }
}

extern "C" void kernel_launch(void* const* d_in, const int* in_sizes, int n_in,
                              void* d_out, int out_size, void* d_ws, size_t ws_size,
                              hipStream_t stream) {
    const float* node_states = (const float*)d_in[0];
    const int*   el          = (const int*)d_in[1];
    const int*   pl          = (const int*)d_in[2];
    const float* msg_W       = (const float*)d_in[3];
    const float* msg_b       = (const float*)d_in[4];
    const float* pos_W       = (const float*)d_in[5];
    const float* pos_b       = (const float*)d_in[6];
    const float* gWih        = (const float*)d_in[7];
    const float* gWhh        = (const float*)d_in[8];
    const float* gbih        = (const float*)d_in[9];
    const float* gbhh        = (const float*)d_in[10];

    float* out  = (float*)d_out;
    float* h    = out;                               // [N,H] final h
    float* out2 = out + (size_t)NN * HH;             // 2 bf16 slabs during steps; node_states at end

    unsigned short* CH0  = (unsigned short*)d_ws;                    // 4 slabs bf16 [N,H]
    unsigned short* CH45 = (unsigned short*)out2;                    // 2 slabs bf16 [N,H]
    unsigned short* MSGB = CH0 + (size_t)4 * NN * HH;                // [N,H] bf16
    unsigned short* GATE = MSGB + (size_t)NN * HH;                   // [1024,H] bf16
    float* INV  = (float*)(GATE + (size_t)PMX * HH + 8);             // [N]
    int* CNT    = (int*)(INV + NN);                                  // [N]
    int* OFF    = CNT + NN;                                          // [N+4]
    int* CUR    = OFF + NN + 4;                                      // [N]
    int* BS     = CUR + NN;                                          // [256]
    int* EDG    = BS + 256;                                          // [600000]
    unsigned short* BPA = (unsigned short*)(EDG + NEDG);             // 12 padded packs
    unsigned short* BPp  = BPA;                                      // 6 prop packs
    unsigned short* BPih = BPA + (size_t)6 * PKS2;                   // ir,iz,in (contig)
    unsigned short* BPhh = BPA + (size_t)9 * PKS2;                   // hr,hz,hn (contig)

    const size_t NH = (size_t)NN * HH;
    hipMemsetAsync(CNT, 0, NN * sizeof(int), stream);
    gate_kernel<<<PMX, 256, 0, stream>>>(pos_W, pos_b, GATE);
    const int pkb = (PKS2 + 255) / 256;
    for (int ty = 0; ty < 6; ++ty)
        pack_kernel<<<pkb, 256, 0, stream>>>(msg_W, 1212, 0, ty * HH, 0, BPp + (size_t)ty * PKS2);
    pack_kernel<<<pkb, 256, 0, stream>>>(gWih, 0, 0,   0, 1, BPih);
    pack_kernel<<<pkb, 256, 0, stream>>>(gWih, 0, 202, 0, 1, BPih + PKS2);
    pack_kernel<<<pkb, 256, 0, stream>>>(gWih, 0, 404, 0, 1, BPih + 2 * PKS2);
    pack_kernel<<<pkb, 256, 0, stream>>>(gWhh, 0, 0,   0, 1, BPhh);
    pack_kernel<<<pkb, 256, 0, stream>>>(gWhh, 0, 202, 0, 1, BPhh + PKS2);
    pack_kernel<<<pkb, 256, 0, stream>>>(gWhh, 0, 404, 0, 1, BPhh + 2 * PKS2);

    const int nsb = (NN + 255) / 256;    // 196
    count_kernel<<<(NEDG + 255) / 256, 256, 0, stream>>>(el, CNT);
    scan1_kernel<<<nsb, 256, 0, stream>>>(CNT, OFF, BS);
    scan2_kernel<<<1, 256, 0, stream>>>(BS, nsb);
    scan3_kernel<<<nsb, 256, 0, stream>>>(OFF, BS, CUR);
    inv_kernel<<<nsb, 256, 0, stream>>>(CNT, INV);
    fill_kernel<<<(NEDG + 255) / 256, 256, 0, stream>>>(el, pl, CUR, EDG);

    const int gblocks = (NN + 63) / 64;  // 782
    const int ewblocks = (NN + 3) / 4;
    for (int step = 0; step < 2; ++step) {
        const float* hsrc = (step == 0) ? node_states : h;
        // 6 chunk GEMMs from h
        gemm9<<<gblocks, 512, 0, stream>>>(hsrc, 1, BPp, 6, msg_b, CH0, CH45, 4);
        // edge aggregation -> MSGB (bf16)
        agg_kernel<<<ewblocks, 256, 0, stream>>>(CH0, CH45, OFF, EDG, GATE, INV, MSGB);
        // gh{r,z,n} = h @ Whh^T  -> CH0 slabs 0..2 (agg already consumed chunks)
        gemm9<<<gblocks, 512, 0, stream>>>(hsrc, 1, BPhh, 3, nullptr, CH0, nullptr, 4);
        // gi{r,z,n} = msg @ Wih^T -> CH0 slab 3, CH45 slabs 0..1
        gemm9<<<gblocks, 512, 0, stream>>>(MSGB, 0, BPih, 3, nullptr,
                                           CH0 + 3 * NH, CH45, 1);
        // streaming GRU elementwise, in-place h
        gru_ew<<<ewblocks, 256, 0, stream>>>(h, hsrc, CH0, CH0 + 3 * NH, CH45, gbih, gbhh);
    }
    hipMemcpyAsync(out2, node_states, NH * sizeof(float), hipMemcpyDeviceToDevice, stream);
}